// Round 2
// baseline (297.266 us; speedup 1.0000x reference)
//
#include <hip/hip_runtime.h>
#include <math.h>

// Problem constants (fixed by the reference's shapes)
#define NROWS   131072      // 32*64*64 spatial positions
#define DFEAT   64          // feature dim (C)
#define KHALF   512         // rows per embedding table
#define HW      4096        // 64*64
#define CHW     262144      // 64*4096
#define NQOUT   8388608     // 32*64*64*64 quantized elements
#define NBLK    512         // vq_main grid: 256 rows/block, 2 blocks/CU

typedef __attribute__((ext_vector_type(8))) short   bf16x8;
typedef __attribute__((ext_vector_type(4))) float   f32x4;

__device__ __forceinline__ unsigned short f2bf(float f) {
    unsigned int u = __float_as_uint(f);
    u += 0x7FFFu + ((u >> 16) & 1u);          // round-to-nearest-even
    return (unsigned short)(u >> 16);
}
__device__ __forceinline__ float bf2f(unsigned short h) {
    return __uint_as_float(((unsigned int)h) << 16);
}

// ---------------------------------------------------------------------------
// Kernel 0 (fused prep): zero ws accumulators + cnh + pack fragments.
//   - tau < 1536: zero {loss, hist, done_ctr} region
//   - tau < 1024: cnh[k] = 0.5*||codes[k]||^2 (fp32 exact)
//   - all 16384:  pack codes into MFMA-B-fragment order, hi/lo bf16 split
// Layout: fragbuf[tile(64)][frag(4)][lane(64)][j(8)] ushort
//   frag 0: hi, k=0..31    frag 1: hi, k=32..63
//   frag 2: lo, k=0..31    frag 3: lo, k=32..63
// lane L of frag f holds code (tile*16 + (L&15)), feats kb..kb+7,
//   kb = (f&1)*32 + (L>>4)*8    -> ready for mfma_f32_16x16x32_bf16 B operand
// ---------------------------------------------------------------------------
__global__ void vq_prep(const float* __restrict__ e0, const float* __restrict__ e1,
                        const float* __restrict__ e2, const int* __restrict__ idxp,
                        float* __restrict__ wsf, float* __restrict__ cnh,
                        unsigned short* __restrict__ fragbuf) {
    int tau = blockIdx.x * 256 + threadIdx.x;   // 64 blocks * 256 = 16384
    if (tau < 1536) wsf[tau] = 0.f;             // loss @0, hist @256.., ctr @1280

    int idx = idxp[0];
    const float* sel = (idx == 2) ? e2 : e1;

    if (tau < 1024) {
        const float* row = (tau < KHALF) ? (e0 + (size_t)tau * DFEAT)
                                         : (sel + (size_t)(tau - KHALF) * DFEAT);
        float s = 0.f;
#pragma unroll
        for (int c = 0; c < DFEAT; ++c) s = fmaf(row[c], row[c], s);
        cnh[tau] = 0.5f * s;
    }

    int tile = tau >> 8;
    int rem  = tau & 255;
    int f    = rem >> 6;
    int L    = rem & 63;
    int code = tile * 16 + (L & 15);
    int kb   = (f & 1) * 32 + (L >> 4) * 8;
    int lo_f = f >> 1;
    const float* src = (code < KHALF) ? (e0 + (size_t)code * DFEAT)
                                      : (sel + (size_t)(code - KHALF) * DFEAT);
    unsigned short* dst = fragbuf + (size_t)tau * 8;
#pragma unroll
    for (int j = 0; j < 8; ++j) {
        float v = src[kb + j];
        unsigned short hb = f2bf(v);
        dst[j] = lo_f ? f2bf(v - bf2f(hb)) : hb;
    }
}

// ---------------------------------------------------------------------------
// Kernel 1: main VQ. Block = 256 threads = 4 waves; 64 rows per wave
// (4 MFMA row-tiles of 16) -> grid 512 -> 2 blocks/CU (known-good ratio:
// 32 MFMAs of compute per 4-fragment code-tile load).
// Per row-tile the 8 MFMAs are split into TWO independent 4-deep chains
// (hi-path / lo-path) -> 8 independent chains per wave for dep-latency ILP.
// Last block (device-scope ticket) computes loss scalar + perplexity.
// ---------------------------------------------------------------------------
__global__ __launch_bounds__(256, 2) void vq_main(
        const float* __restrict__ x,
        const float* __restrict__ e0, const float* __restrict__ e1,
        const float* __restrict__ e2, const int* __restrict__ idxp,
        const float* __restrict__ cnh, const unsigned short* __restrict__ fragbuf,
        float* __restrict__ out, float* __restrict__ loss_acc,
        int* __restrict__ hist, int* __restrict__ done_ctr) {
    __shared__ float  xsq_s[256];
    __shared__ float  sc_s[256];
    __shared__ int    bk_s[256];
    __shared__ int    islast_s;
    __shared__ double pp_s[4];

    const int t = threadIdx.x;
    const int w = t >> 6;          // wave in block
    const int L = t & 63;          // lane
    const int q = L >> 4;          // quad
    const int m = L & 15;

    const int rowbase = blockIdx.x * 256;   // 512 blocks; never straddles an image
    const int n  = rowbase >> 12;
    const int s0 = rowbase & 4095;

    const int idx = idxp[0];
    const float* sel = (idx == 2) ? e2 : e1;
    const int ntiles = (idx == 0) ? 32 : 64;

    // ---- A fragments: 4 row-tiles of 16 rows, hi/lo bf16 + ||x||^2 ----
    bf16x8 ahi[4][2], alo[4][2];
    const float* xb = x + (size_t)n * CHW + (s0 + w * 64);
#pragma unroll
    for (int rt = 0; rt < 4; ++rt) {
        const float* xr = xb + rt * 16 + m;
        float xs = 0.f;
#pragma unroll
        for (int h = 0; h < 2; ++h) {
#pragma unroll
            for (int j = 0; j < 8; ++j) {
                int c = h * 32 + q * 8 + j;
                float v = xr[(size_t)c * HW];
                xs = fmaf(v, v, xs);
                unsigned short hb = f2bf(v);
                unsigned short lb = f2bf(v - bf2f(hb));
                ahi[rt][h][j] = (short)hb;
                alo[rt][h][j] = (short)lb;
            }
        }
        // full ||x_row||^2: row features live in lanes {m, m+16, m+32, m+48}
        xs += __shfl_xor(xs, 16, 64);
        xs += __shfl_xor(xs, 32, 64);
        if (q == 0) xsq_s[w * 64 + rt * 16 + m] = xs;
    }

    // ---- stream 64 code tiles; score = x.c - 0.5||c||^2, argMAX ----
    const bf16x8* fb = (const bf16x8*)fragbuf;
    float best[16];
    int   bidx[16];
#pragma unroll
    for (int i = 0; i < 16; ++i) { best[i] = -3.4e38f; bidx[i] = 0; }

    bf16x8 bc0 = fb[0 * 64 + L];
    bf16x8 bc1 = fb[1 * 64 + L];
    bf16x8 bc2 = fb[2 * 64 + L];
    bf16x8 bc3 = fb[3 * 64 + L];
    float  cnc = cnh[m];

    for (int tt = 0; tt < ntiles; ++tt) {
        const int tn = (tt + 1 < ntiles) ? tt + 1 : tt;
        bf16x8 bn0 = fb[(tn * 4 + 0) * 64 + L];
        bf16x8 bn1 = fb[(tn * 4 + 1) * 64 + L];
        bf16x8 bn2 = fb[(tn * 4 + 2) * 64 + L];
        bf16x8 bn3 = fb[(tn * 4 + 3) * 64 + L];
        float  cnn = cnh[tn * 16 + m];
        const int kt = tt * 16 + m;    // this lane's candidate code id (col = m)
#pragma unroll
        for (int rt = 0; rt < 4; ++rt) {
            // two independent 4-deep chains: hi-path and lo-path
            f32x4 a0 = {0.f, 0.f, 0.f, 0.f};
            f32x4 a1 = {0.f, 0.f, 0.f, 0.f};
            a0 = __builtin_amdgcn_mfma_f32_16x16x32_bf16(ahi[rt][0], bc0, a0, 0, 0, 0); // hi*hi
            a1 = __builtin_amdgcn_mfma_f32_16x16x32_bf16(alo[rt][0], bc0, a1, 0, 0, 0); // lo*hi
            a0 = __builtin_amdgcn_mfma_f32_16x16x32_bf16(ahi[rt][1], bc1, a0, 0, 0, 0);
            a1 = __builtin_amdgcn_mfma_f32_16x16x32_bf16(alo[rt][1], bc1, a1, 0, 0, 0);
            a0 = __builtin_amdgcn_mfma_f32_16x16x32_bf16(ahi[rt][0], bc2, a0, 0, 0, 0); // hi*lo
            a1 = __builtin_amdgcn_mfma_f32_16x16x32_bf16(alo[rt][0], bc2, a1, 0, 0, 0); // lo*lo
            a0 = __builtin_amdgcn_mfma_f32_16x16x32_bf16(ahi[rt][1], bc3, a0, 0, 0, 0);
            a1 = __builtin_amdgcn_mfma_f32_16x16x32_bf16(alo[rt][1], bc3, a1, 0, 0, 0);
#pragma unroll
            for (int r = 0; r < 4; ++r) {
                float s = (a0[r] + a1[r]) - cnc;
                if (s > best[rt * 4 + r]) { best[rt * 4 + r] = s; bidx[rt * 4 + r] = kt; }
            }
        }
        bc0 = bn0; bc1 = bn1; bc2 = bn2; bc3 = bn3; cnc = cnn;
    }

    // ---- reduce argmax across the 16 cols (lane bits 0-3) ----
#pragma unroll
    for (int i = 0; i < 16; ++i) {
        float b = best[i]; int k = bidx[i];
#pragma unroll
        for (int off = 1; off < 16; off <<= 1) {
            float ob = __shfl_xor(b, off, 64);
            int   ok = __shfl_xor(k, off, 64);
            if (ob > b || (ob == b && ok < k)) { b = ob; k = ok; }
        }
        if (m == 0) {   // D row = q*4 + r within tile rt = i>>2
            int row = w * 64 + (i >> 2) * 16 + q * 4 + (i & 3);
            sc_s[row] = b; bk_s[row] = k;
        }
    }
    __syncthreads();

    // ---- epilogue: one thread per row ----
    const int k   = bk_s[t];
    float dist    = xsq_s[t] - 2.f * sc_s[t];   // ||x||^2 - 2x.c + ||c||^2
    float l = dist;
#pragma unroll
    for (int off = 32; off > 0; off >>= 1) l += __shfl_down(l, off, 64);
    if (L == 0) atomicAdd(loss_acc, l);
    atomicAdd(&hist[k], 1);

    const float* cp = (k < KHALF) ? (e0 + (size_t)k * DFEAT)
                                  : (sel + (size_t)(k - KHALF) * DFEAT);
    const float4* cp4 = (const float4*)cp;
    float* op = out + (size_t)n * CHW + (s0 + t);
#pragma unroll
    for (int c4 = 0; c4 < 16; ++c4) {
        float4 v = cp4[c4];
        op[(size_t)(4 * c4 + 0) * HW] = v.x;
        op[(size_t)(4 * c4 + 1) * HW] = v.y;
        op[(size_t)(4 * c4 + 2) * HW] = v.z;
        op[(size_t)(4 * c4 + 3) * HW] = v.w;
    }

    // ---- finalize: last block computes loss scalar + perplexity ----
    __threadfence();
    __syncthreads();
    if (t == 0) {
        int tk = __hip_atomic_fetch_add(done_ctr, 1, __ATOMIC_ACQ_REL,
                                        __HIP_MEMORY_SCOPE_AGENT);
        islast_s = (tk == NBLK - 1);
    }
    __syncthreads();
    if (islast_s) {
        double term = 0.0;
#pragma unroll
        for (int j = 0; j < 4; ++j) {
            int c = __hip_atomic_load(&hist[t * 4 + j], __ATOMIC_RELAXED,
                                      __HIP_MEMORY_SCOPE_AGENT);
            double p = (double)c / (double)NROWS;
            term += p * log(p + 1e-10);   // p==0 -> exactly 0
        }
#pragma unroll
        for (int off = 32; off > 0; off >>= 1) term += __shfl_down(term, off, 64);
        if (L == 0) pp_s[w] = term;
        __syncthreads();
        if (t == 0) {
            double s = pp_s[0] + pp_s[1] + pp_s[2] + pp_s[3];
            float lacc = __hip_atomic_load(loss_acc, __ATOMIC_RELAXED,
                                           __HIP_MEMORY_SCOPE_AGENT);
            out[NQOUT + 1] = (float)exp(-s);                   // perplexity
            out[NQOUT]     = 1.25f * (lacc / (float)NQOUT);    // q_loss + 0.25*e_loss
        }
    }
}

// ---------------------------------------------------------------------------
extern "C" void kernel_launch(void* const* d_in, const int* in_sizes, int n_in,
                              void* d_out, int out_size, void* d_ws, size_t ws_size,
                              hipStream_t stream) {
    const float* x  = (const float*)d_in[0];
    const float* e0 = (const float*)d_in[1];
    const float* e1 = (const float*)d_in[2];
    const float* e2 = (const float*)d_in[3];
    const int* idxp = (const int*)d_in[4];
    float* out = (float*)d_out;

    // ws layout (floats): [0] loss | [256..1280) hist | [1280] done_ctr
    //                     [2048..3072) cnh | [4096..) fragbuf: 131072 ushort
    float* wsf      = (float*)d_ws;
    float* loss_acc = wsf;
    int*   hist     = (int*)(wsf + 256);
    int*   done_ctr = (int*)(wsf + 1280);
    float* cnh      = wsf + 2048;
    unsigned short* fragbuf = (unsigned short*)(wsf + 4096);

    vq_prep<<<64, 256, 0, stream>>>(e0, e1, e2, idxp, wsf, cnh, fragbuf);
    vq_main<<<NBLK, 256, 0, stream>>>(x, e0, e1, e2, idxp, cnh, fragbuf,
                                      out, loss_acc, hist, done_ctr);
}

// Round 3
// 219.694 us; speedup vs baseline: 1.3531x; 1.3531x over previous
//
#include <hip/hip_runtime.h>
#include <math.h>

// Problem constants (fixed by the reference's shapes)
#define NROWS   131072      // 32*64*64 spatial positions
#define DFEAT   64          // feature dim (C)
#define KHALF   512         // rows per embedding table
#define HW      4096        // 64*64
#define CHW     262144      // 64*4096
#define NQOUT   8388608     // 32*64*64*64 quantized elements
#define NBLK    512         // vq_main grid: 256 rows/block, 2 blocks/CU

typedef __attribute__((ext_vector_type(8))) short   bf16x8;
typedef __attribute__((ext_vector_type(4))) float   f32x4;

__device__ __forceinline__ unsigned short f2bf(float f) {
    unsigned int u = __float_as_uint(f);
    u += 0x7FFFu + ((u >> 16) & 1u);          // round-to-nearest-even
    return (unsigned short)(u >> 16);
}
__device__ __forceinline__ float bf2f(unsigned short h) {
    return __uint_as_float(((unsigned int)h) << 16);
}

// ---------------------------------------------------------------------------
// Kernel 0 (fused prep): zero ws accumulators + cnh + pack fragments.
//   - tau < 1536: zero {loss, hist} region
//   - tau < 1024: cnh[k] = 0.5*||codes[k]||^2 (fp32 exact)
//   - all 16384:  pack codes into MFMA-B-fragment order, hi/lo bf16 split
// Layout: fragbuf[tile(64)][frag(4)][lane(64)][j(8)] ushort
//   frag 0: hi, k=0..31    frag 1: hi, k=32..63
//   frag 2: lo, k=0..31    frag 3: lo, k=32..63
// lane L of frag f holds code (tile*16 + (L&15)), feats kb..kb+7,
//   kb = (f&1)*32 + (L>>4)*8    -> ready for mfma_f32_16x16x32_bf16 B operand
// NOTE: no device-scope fences anywhere in this file. The agent-scope
// __threadfence() ticket-finalize tried in rounds 1-2 emitted per-wave
// buffer_wbl2/buffer_inv (2048 L2 writebacks) and doubled vq_main's time.
// Cross-kernel visibility via the dispatch boundary (one L2 writeback total).
// ---------------------------------------------------------------------------
__global__ void vq_prep(const float* __restrict__ e0, const float* __restrict__ e1,
                        const float* __restrict__ e2, const int* __restrict__ idxp,
                        float* __restrict__ wsf, float* __restrict__ cnh,
                        unsigned short* __restrict__ fragbuf) {
    int tau = blockIdx.x * 256 + threadIdx.x;   // 64 blocks * 256 = 16384
    if (tau < 1536) wsf[tau] = 0.f;             // loss @0, hist @256..

    int idx = idxp[0];
    const float* sel = (idx == 2) ? e2 : e1;

    if (tau < 1024) {
        const float* row = (tau < KHALF) ? (e0 + (size_t)tau * DFEAT)
                                         : (sel + (size_t)(tau - KHALF) * DFEAT);
        float s = 0.f;
#pragma unroll
        for (int c = 0; c < DFEAT; ++c) s = fmaf(row[c], row[c], s);
        cnh[tau] = 0.5f * s;
    }

    int tile = tau >> 8;
    int rem  = tau & 255;
    int f    = rem >> 6;
    int L    = rem & 63;
    int code = tile * 16 + (L & 15);
    int kb   = (f & 1) * 32 + (L >> 4) * 8;
    int lo_f = f >> 1;
    const float* src = (code < KHALF) ? (e0 + (size_t)code * DFEAT)
                                      : (sel + (size_t)(code - KHALF) * DFEAT);
    unsigned short* dst = fragbuf + (size_t)tau * 8;
#pragma unroll
    for (int j = 0; j < 8; ++j) {
        float v = src[kb + j];
        unsigned short hb = f2bf(v);
        dst[j] = lo_f ? f2bf(v - bf2f(hb)) : hb;
    }
}

// ---------------------------------------------------------------------------
// Kernel 1: main VQ. Block = 256 threads = 4 waves; 64 rows per wave
// (4 MFMA row-tiles of 16) -> grid 512 -> 2 blocks/CU (known-good ratio:
// 32 MFMAs of compute per 4-fragment code-tile load).
// Per row-tile the 8 MFMAs run as TWO independent 4-deep chains
// (hi-path / lo-path) -> 8 independent chains per wave for dep-latency ILP.
// ---------------------------------------------------------------------------
__global__ __launch_bounds__(256, 2) void vq_main(
        const float* __restrict__ x,
        const float* __restrict__ e0, const float* __restrict__ e1,
        const float* __restrict__ e2, const int* __restrict__ idxp,
        const float* __restrict__ cnh, const unsigned short* __restrict__ fragbuf,
        float* __restrict__ out, float* __restrict__ loss_acc,
        int* __restrict__ hist) {
    __shared__ float xsq_s[256];
    __shared__ float sc_s[256];
    __shared__ int   bk_s[256];

    const int t = threadIdx.x;
    const int w = t >> 6;          // wave in block
    const int L = t & 63;          // lane
    const int q = L >> 4;          // quad
    const int m = L & 15;

    const int rowbase = blockIdx.x * 256;   // 512 blocks; never straddles an image
    const int n  = rowbase >> 12;
    const int s0 = rowbase & 4095;

    const int idx = idxp[0];
    const float* sel = (idx == 2) ? e2 : e1;
    const int ntiles = (idx == 0) ? 32 : 64;

    // ---- A fragments: 4 row-tiles of 16 rows, hi/lo bf16 + ||x||^2 ----
    bf16x8 ahi[4][2], alo[4][2];
    const float* xb = x + (size_t)n * CHW + (s0 + w * 64);
#pragma unroll
    for (int rt = 0; rt < 4; ++rt) {
        const float* xr = xb + rt * 16 + m;
        float xs = 0.f;
#pragma unroll
        for (int h = 0; h < 2; ++h) {
#pragma unroll
            for (int j = 0; j < 8; ++j) {
                int c = h * 32 + q * 8 + j;
                float v = xr[(size_t)c * HW];
                xs = fmaf(v, v, xs);
                unsigned short hb = f2bf(v);
                unsigned short lb = f2bf(v - bf2f(hb));
                ahi[rt][h][j] = (short)hb;
                alo[rt][h][j] = (short)lb;
            }
        }
        // full ||x_row||^2: row features live in lanes {m, m+16, m+32, m+48}
        xs += __shfl_xor(xs, 16, 64);
        xs += __shfl_xor(xs, 32, 64);
        if (q == 0) xsq_s[w * 64 + rt * 16 + m] = xs;
    }

    // ---- stream 64 code tiles; score = x.c - 0.5||c||^2, argMAX ----
    const bf16x8* fb = (const bf16x8*)fragbuf;
    float best[16];
    int   bidx[16];
#pragma unroll
    for (int i = 0; i < 16; ++i) { best[i] = -3.4e38f; bidx[i] = 0; }

    bf16x8 bc0 = fb[0 * 64 + L];
    bf16x8 bc1 = fb[1 * 64 + L];
    bf16x8 bc2 = fb[2 * 64 + L];
    bf16x8 bc3 = fb[3 * 64 + L];
    float  cnc = cnh[m];

    for (int tt = 0; tt < ntiles; ++tt) {
        const int tn = (tt + 1 < ntiles) ? tt + 1 : tt;
        bf16x8 bn0 = fb[(tn * 4 + 0) * 64 + L];
        bf16x8 bn1 = fb[(tn * 4 + 1) * 64 + L];
        bf16x8 bn2 = fb[(tn * 4 + 2) * 64 + L];
        bf16x8 bn3 = fb[(tn * 4 + 3) * 64 + L];
        float  cnn = cnh[tn * 16 + m];
        const int kt = tt * 16 + m;    // this lane's candidate code id (col = m)
#pragma unroll
        for (int rt = 0; rt < 4; ++rt) {
            // two independent 4-deep chains: hi-path and lo-path
            f32x4 a0 = {0.f, 0.f, 0.f, 0.f};
            f32x4 a1 = {0.f, 0.f, 0.f, 0.f};
            a0 = __builtin_amdgcn_mfma_f32_16x16x32_bf16(ahi[rt][0], bc0, a0, 0, 0, 0); // hi*hi
            a1 = __builtin_amdgcn_mfma_f32_16x16x32_bf16(alo[rt][0], bc0, a1, 0, 0, 0); // lo*hi
            a0 = __builtin_amdgcn_mfma_f32_16x16x32_bf16(ahi[rt][1], bc1, a0, 0, 0, 0);
            a1 = __builtin_amdgcn_mfma_f32_16x16x32_bf16(alo[rt][1], bc1, a1, 0, 0, 0);
            a0 = __builtin_amdgcn_mfma_f32_16x16x32_bf16(ahi[rt][0], bc2, a0, 0, 0, 0); // hi*lo
            a1 = __builtin_amdgcn_mfma_f32_16x16x32_bf16(alo[rt][0], bc2, a1, 0, 0, 0); // lo*lo
            a0 = __builtin_amdgcn_mfma_f32_16x16x32_bf16(ahi[rt][1], bc3, a0, 0, 0, 0);
            a1 = __builtin_amdgcn_mfma_f32_16x16x32_bf16(alo[rt][1], bc3, a1, 0, 0, 0);
#pragma unroll
            for (int r = 0; r < 4; ++r) {
                float s = (a0[r] + a1[r]) - cnc;
                if (s > best[rt * 4 + r]) { best[rt * 4 + r] = s; bidx[rt * 4 + r] = kt; }
            }
        }
        bc0 = bn0; bc1 = bn1; bc2 = bn2; bc3 = bn3; cnc = cnn;
    }

    // ---- reduce argmax across the 16 cols (lane bits 0-3) ----
#pragma unroll
    for (int i = 0; i < 16; ++i) {
        float b = best[i]; int k = bidx[i];
#pragma unroll
        for (int off = 1; off < 16; off <<= 1) {
            float ob = __shfl_xor(b, off, 64);
            int   ok = __shfl_xor(k, off, 64);
            if (ob > b || (ob == b && ok < k)) { b = ob; k = ok; }
        }
        if (m == 0) {   // D row = q*4 + r within tile rt = i>>2
            int row = w * 64 + (i >> 2) * 16 + q * 4 + (i & 3);
            sc_s[row] = b; bk_s[row] = k;
        }
    }
    __syncthreads();

    // ---- epilogue: one thread per row ----
    const int k   = bk_s[t];
    float dist    = xsq_s[t] - 2.f * sc_s[t];   // ||x||^2 - 2x.c + ||c||^2
    float l = dist;
#pragma unroll
    for (int off = 32; off > 0; off >>= 1) l += __shfl_down(l, off, 64);
    if (L == 0) atomicAdd(loss_acc, l);
    atomicAdd(&hist[k], 1);

    const float* cp = (k < KHALF) ? (e0 + (size_t)k * DFEAT)
                                  : (sel + (size_t)(k - KHALF) * DFEAT);
    const float4* cp4 = (const float4*)cp;
    float* op = out + (size_t)n * CHW + (s0 + t);
#pragma unroll
    for (int c4 = 0; c4 < 16; ++c4) {
        float4 v = cp4[c4];
        op[(size_t)(4 * c4 + 0) * HW] = v.x;
        op[(size_t)(4 * c4 + 1) * HW] = v.y;
        op[(size_t)(4 * c4 + 2) * HW] = v.z;
        op[(size_t)(4 * c4 + 3) * HW] = v.w;
    }
}

// ---------------------------------------------------------------------------
// Kernel 2: finalize — loss scalar + perplexity from histogram. One block.
// Cross-kernel visibility of hist/loss comes from the dispatch boundary.
// ---------------------------------------------------------------------------
__global__ void vq_finalize(const float* __restrict__ wsf, const int* __restrict__ hist,
                            float* __restrict__ out) {
    __shared__ double partial[16];
    const int t = threadIdx.x;          // 1024 threads, one per bin
    double p = (double)hist[t] / (double)NROWS;
    double term = p * log(p + 1e-10);   // p==0 -> exactly 0
#pragma unroll
    for (int off = 32; off > 0; off >>= 1) term += __shfl_down(term, off, 64);
    if ((t & 63) == 0) partial[t >> 6] = term;
    __syncthreads();
    if (t == 0) {
        double s = 0.0;
        for (int i = 0; i < 16; ++i) s += partial[i];
        out[NQOUT + 1] = (float)exp(-s);                       // perplexity
        out[NQOUT]     = 1.25f * (wsf[0] / (float)NQOUT);      // q_loss + 0.25*e_loss
    }
}

// ---------------------------------------------------------------------------
extern "C" void kernel_launch(void* const* d_in, const int* in_sizes, int n_in,
                              void* d_out, int out_size, void* d_ws, size_t ws_size,
                              hipStream_t stream) {
    const float* x  = (const float*)d_in[0];
    const float* e0 = (const float*)d_in[1];
    const float* e1 = (const float*)d_in[2];
    const float* e2 = (const float*)d_in[3];
    const int* idxp = (const int*)d_in[4];
    float* out = (float*)d_out;

    // ws layout (floats): [0] loss | [256..1280) hist
    //                     [2048..3072) cnh | [4096..) fragbuf: 131072 ushort
    float* wsf      = (float*)d_ws;
    float* loss_acc = wsf;
    int*   hist     = (int*)(wsf + 256);
    float* cnh      = wsf + 2048;
    unsigned short* fragbuf = (unsigned short*)(wsf + 4096);

    vq_prep<<<64, 256, 0, stream>>>(e0, e1, e2, idxp, wsf, cnh, fragbuf);
    vq_main<<<NBLK, 256, 0, stream>>>(x, e0, e1, e2, idxp, cnh, fragbuf,
                                      out, loss_acc, hist);
    vq_finalize<<<1, 1024, 0, stream>>>(wsf, hist, out);
}

// Round 4
// 183.537 us; speedup vs baseline: 1.6196x; 1.1970x over previous
//
#include <hip/hip_runtime.h>
#include <math.h>

// Problem constants (fixed by the reference's shapes)
#define NROWS   131072      // 32*64*64 spatial positions
#define DFEAT   64          // feature dim (C)
#define KHALF   512         // rows per embedding table
#define HW      4096        // 64*64
#define CHW     262144      // 64*4096
#define NQOUT   8388608     // 32*64*64*64 quantized elements
#define NBLK    512         // vq_main grid: 256 rows/block, 2 blocks/CU

typedef __attribute__((ext_vector_type(8))) short   bf16x8;
typedef __attribute__((ext_vector_type(4))) float   f32x4;

__device__ __forceinline__ unsigned short f2bf(float f) {
    unsigned int u = __float_as_uint(f);
    u += 0x7FFFu + ((u >> 16) & 1u);          // round-to-nearest-even
    return (unsigned short)(u >> 16);
}
__device__ __forceinline__ float bf2f(unsigned short h) {
    return __uint_as_float(((unsigned int)h) << 16);
}

// ---------------------------------------------------------------------------
// Kernel 0 (fused prep): zero ws accumulators + cnh + pack fragments.
//   - tau < 1536: zero {loss, hist} region
//   - tau < 1024: cnh[k] = 0.5*||codes[k]||^2 (fp32 exact)
//   - all 16384:  pack codes into MFMA-B-fragment order, hi/lo bf16 split
// Layout: fragbuf[tile(64)][frag(4)][lane(64)][j(8)] ushort
//   frag 0: hi, k=0..31    frag 1: hi, k=32..63
//   frag 2: lo, k=0..31    frag 3: lo, k=32..63
// lane L of frag f holds code (tile*16 + (L&15)), feats kb..kb+7,
//   kb = (f&1)*32 + (L>>4)*8    -> ready for mfma_f32_16x16x32_bf16 B operand
// NOTE: no device-scope fences anywhere in this file. The agent-scope
// __threadfence() ticket-finalize tried in rounds 1-2 emitted per-wave
// L2 writeback/invalidate (2048 of them) and doubled vq_main's time.
// Cross-kernel visibility via the dispatch boundary (one L2 writeback total).
// ---------------------------------------------------------------------------
__global__ void vq_prep(const float* __restrict__ e0, const float* __restrict__ e1,
                        const float* __restrict__ e2, const int* __restrict__ idxp,
                        float* __restrict__ wsf, float* __restrict__ cnh,
                        unsigned short* __restrict__ fragbuf) {
    int tau = blockIdx.x * 256 + threadIdx.x;   // 64 blocks * 256 = 16384
    if (tau < 1536) wsf[tau] = 0.f;             // loss @0, hist @256..

    int idx = idxp[0];
    const float* sel = (idx == 2) ? e2 : e1;

    if (tau < 1024) {
        const float* row = (tau < KHALF) ? (e0 + (size_t)tau * DFEAT)
                                         : (sel + (size_t)(tau - KHALF) * DFEAT);
        float s = 0.f;
#pragma unroll
        for (int c = 0; c < DFEAT; ++c) s = fmaf(row[c], row[c], s);
        cnh[tau] = 0.5f * s;
    }

    int tile = tau >> 8;
    int rem  = tau & 255;
    int f    = rem >> 6;
    int L    = rem & 63;
    int code = tile * 16 + (L & 15);
    int kb   = (f & 1) * 32 + (L >> 4) * 8;
    int lo_f = f >> 1;
    const float* src = (code < KHALF) ? (e0 + (size_t)code * DFEAT)
                                      : (sel + (size_t)(code - KHALF) * DFEAT);
    unsigned short* dst = fragbuf + (size_t)tau * 8;
#pragma unroll
    for (int j = 0; j < 8; ++j) {
        float v = src[kb + j];
        unsigned short hb = f2bf(v);
        dst[j] = lo_f ? f2bf(v - bf2f(hb)) : hb;
    }
}

// ---------------------------------------------------------------------------
// Kernel 1: main VQ. Block = 256 threads = 4 waves; 64 rows per wave
// (4 MFMA row-tiles of 16) -> grid 512 -> 2 blocks/CU (verified-good ratio:
// 32 MFMAs of compute per 4-fragment code-tile load).
// Inner loop is the round-0 verified schedule: ONE 8-deep MFMA chain per
// row-tile (dual-chain split regressed in r3). Tile loop unrolled 2x with
// ping-pong B-register sets: no bc=bn copies, prefetch wait off the
// critical path. ntiles is always even (32 or 64).
// ---------------------------------------------------------------------------
#define TILE_STEP(BC0, BC1, BC2, BC3, CNC, BN0, BN1, BN2, BN3, CNN, TT, TL)   \
    {                                                                          \
        const int tl_ = (TL);                                                  \
        BN0 = fb[(tl_ * 4 + 0) * 64 + L];                                      \
        BN1 = fb[(tl_ * 4 + 1) * 64 + L];                                      \
        BN2 = fb[(tl_ * 4 + 2) * 64 + L];                                      \
        BN3 = fb[(tl_ * 4 + 3) * 64 + L];                                      \
        CNN = cnh[tl_ * 16 + m];                                               \
        const int kt_ = (TT) * 16 + m;                                         \
        _Pragma("unroll")                                                      \
        for (int rt = 0; rt < 4; ++rt) {                                       \
            f32x4 acc = {0.f, 0.f, 0.f, 0.f};                                  \
            acc = __builtin_amdgcn_mfma_f32_16x16x32_bf16(ahi[rt][0], BC0, acc, 0, 0, 0); \
            acc = __builtin_amdgcn_mfma_f32_16x16x32_bf16(ahi[rt][1], BC1, acc, 0, 0, 0); \
            acc = __builtin_amdgcn_mfma_f32_16x16x32_bf16(ahi[rt][0], BC2, acc, 0, 0, 0); \
            acc = __builtin_amdgcn_mfma_f32_16x16x32_bf16(ahi[rt][1], BC3, acc, 0, 0, 0); \
            acc = __builtin_amdgcn_mfma_f32_16x16x32_bf16(alo[rt][0], BC0, acc, 0, 0, 0); \
            acc = __builtin_amdgcn_mfma_f32_16x16x32_bf16(alo[rt][1], BC1, acc, 0, 0, 0); \
            acc = __builtin_amdgcn_mfma_f32_16x16x32_bf16(alo[rt][0], BC2, acc, 0, 0, 0); \
            acc = __builtin_amdgcn_mfma_f32_16x16x32_bf16(alo[rt][1], BC3, acc, 0, 0, 0); \
            _Pragma("unroll")                                                  \
            for (int r = 0; r < 4; ++r) {                                      \
                float s = acc[r] - CNC;                                        \
                if (s > best[rt * 4 + r]) { best[rt * 4 + r] = s; bidx[rt * 4 + r] = kt_; } \
            }                                                                  \
        }                                                                      \
    }

__global__ __launch_bounds__(256, 2) void vq_main(
        const float* __restrict__ x,
        const float* __restrict__ e0, const float* __restrict__ e1,
        const float* __restrict__ e2, const int* __restrict__ idxp,
        const float* __restrict__ cnh, const unsigned short* __restrict__ fragbuf,
        float* __restrict__ out, float* __restrict__ loss_acc,
        int* __restrict__ hist) {
    __shared__ float xsq_s[256];
    __shared__ float sc_s[256];
    __shared__ int   bk_s[256];

    const int t = threadIdx.x;
    const int w = t >> 6;          // wave in block
    const int L = t & 63;          // lane
    const int q = L >> 4;          // quad
    const int m = L & 15;

    const int rowbase = blockIdx.x * 256;   // 512 blocks; never straddles an image
    const int n  = rowbase >> 12;
    const int s0 = rowbase & 4095;

    const int idx = idxp[0];
    const float* sel = (idx == 2) ? e2 : e1;
    const int ntiles = (idx == 0) ? 32 : 64;   // always even

    // ---- A fragments: 4 row-tiles of 16 rows, hi/lo bf16 + ||x||^2 ----
    bf16x8 ahi[4][2], alo[4][2];
    const float* xb = x + (size_t)n * CHW + (s0 + w * 64);
#pragma unroll
    for (int rt = 0; rt < 4; ++rt) {
        const float* xr = xb + rt * 16 + m;
        float xs = 0.f;
#pragma unroll
        for (int h = 0; h < 2; ++h) {
#pragma unroll
            for (int j = 0; j < 8; ++j) {
                int c = h * 32 + q * 8 + j;
                float v = xr[(size_t)c * HW];
                xs = fmaf(v, v, xs);
                unsigned short hb = f2bf(v);
                unsigned short lb = f2bf(v - bf2f(hb));
                ahi[rt][h][j] = (short)hb;
                alo[rt][h][j] = (short)lb;
            }
        }
        // full ||x_row||^2: row features live in lanes {m, m+16, m+32, m+48}
        xs += __shfl_xor(xs, 16, 64);
        xs += __shfl_xor(xs, 32, 64);
        if (q == 0) xsq_s[w * 64 + rt * 16 + m] = xs;
    }

    // ---- stream 64 code tiles; score = x.c - 0.5||c||^2, argMAX ----
    const bf16x8* fb = (const bf16x8*)fragbuf;
    float best[16];
    int   bidx[16];
#pragma unroll
    for (int i = 0; i < 16; ++i) { best[i] = -3.4e38f; bidx[i] = 0; }

    bf16x8 X0 = fb[0 * 64 + L];
    bf16x8 X1 = fb[1 * 64 + L];
    bf16x8 X2 = fb[2 * 64 + L];
    bf16x8 X3 = fb[3 * 64 + L];
    float  Xc = cnh[m];
    bf16x8 Y0, Y1, Y2, Y3;
    float  Yc;

    for (int tt = 0; tt < ntiles; tt += 2) {
        TILE_STEP(X0, X1, X2, X3, Xc, Y0, Y1, Y2, Y3, Yc, tt, tt + 1);
        const int t2 = (tt + 2 < ntiles) ? tt + 2 : ntiles - 1;
        TILE_STEP(Y0, Y1, Y2, Y3, Yc, X0, X1, X2, X3, Xc, tt + 1, t2);
    }

    // ---- reduce argmax across the 16 cols (lane bits 0-3) ----
#pragma unroll
    for (int i = 0; i < 16; ++i) {
        float b = best[i]; int k = bidx[i];
#pragma unroll
        for (int off = 1; off < 16; off <<= 1) {
            float ob = __shfl_xor(b, off, 64);
            int   ok = __shfl_xor(k, off, 64);
            if (ob > b || (ob == b && ok < k)) { b = ob; k = ok; }
        }
        if (m == 0) {   // D row = q*4 + r within tile rt = i>>2
            int row = w * 64 + (i >> 2) * 16 + q * 4 + (i & 3);
            sc_s[row] = b; bk_s[row] = k;
        }
    }
    __syncthreads();

    // ---- epilogue: one thread per row ----
    const int k   = bk_s[t];
    float dist    = xsq_s[t] - 2.f * sc_s[t];   // ||x||^2 - 2x.c + ||c||^2
    float l = dist;
#pragma unroll
    for (int off = 32; off > 0; off >>= 1) l += __shfl_down(l, off, 64);
    if (L == 0) atomicAdd(loss_acc, l);
    atomicAdd(&hist[k], 1);

    const float* cp = (k < KHALF) ? (e0 + (size_t)k * DFEAT)
                                  : (sel + (size_t)(k - KHALF) * DFEAT);
    const float4* cp4 = (const float4*)cp;
    float* op = out + (size_t)n * CHW + (s0 + t);
#pragma unroll
    for (int c4 = 0; c4 < 16; ++c4) {
        float4 v = cp4[c4];
        op[(size_t)(4 * c4 + 0) * HW] = v.x;
        op[(size_t)(4 * c4 + 1) * HW] = v.y;
        op[(size_t)(4 * c4 + 2) * HW] = v.z;
        op[(size_t)(4 * c4 + 3) * HW] = v.w;
    }
}

// ---------------------------------------------------------------------------
// Kernel 2: finalize — loss scalar + perplexity from histogram. One block.
// Cross-kernel visibility of hist/loss comes from the dispatch boundary.
// ---------------------------------------------------------------------------
__global__ void vq_finalize(const float* __restrict__ wsf, const int* __restrict__ hist,
                            float* __restrict__ out) {
    __shared__ double partial[16];
    const int t = threadIdx.x;          // 1024 threads, one per bin
    double p = (double)hist[t] / (double)NROWS;
    double term = p * log(p + 1e-10);   // p==0 -> exactly 0
#pragma unroll
    for (int off = 32; off > 0; off >>= 1) term += __shfl_down(term, off, 64);
    if ((t & 63) == 0) partial[t >> 6] = term;
    __syncthreads();
    if (t == 0) {
        double s = 0.0;
        for (int i = 0; i < 16; ++i) s += partial[i];
        out[NQOUT + 1] = (float)exp(-s);                       // perplexity
        out[NQOUT]     = 1.25f * (wsf[0] / (float)NQOUT);      // q_loss + 0.25*e_loss
    }
}

// ---------------------------------------------------------------------------
extern "C" void kernel_launch(void* const* d_in, const int* in_sizes, int n_in,
                              void* d_out, int out_size, void* d_ws, size_t ws_size,
                              hipStream_t stream) {
    const float* x  = (const float*)d_in[0];
    const float* e0 = (const float*)d_in[1];
    const float* e1 = (const float*)d_in[2];
    const float* e2 = (const float*)d_in[3];
    const int* idxp = (const int*)d_in[4];
    float* out = (float*)d_out;

    // ws layout (floats): [0] loss | [256..1280) hist
    //                     [2048..3072) cnh | [4096..) fragbuf: 131072 ushort
    float* wsf      = (float*)d_ws;
    float* loss_acc = wsf;
    int*   hist     = (int*)(wsf + 256);
    float* cnh      = wsf + 2048;
    unsigned short* fragbuf = (unsigned short*)(wsf + 4096);

    vq_prep<<<64, 256, 0, stream>>>(e0, e1, e2, idxp, wsf, cnh, fragbuf);
    vq_main<<<NBLK, 256, 0, stream>>>(x, e0, e1, e2, idxp, cnh, fragbuf,
                                      out, loss_acc, hist);
    vq_finalize<<<1, 1024, 0, stream>>>(wsf, hist, out);
}